// Round 7
// baseline (517.478 us; speedup 1.0000x reference)
//
#include <hip/hip_runtime.h>
#include <hip/hip_bf16.h>
#include <stdint.h>

// Problem constants (fixed by reference: M=4096, K=4096, N=12288, group=128)
constexpr int Mdim = 4096;
constexpr int Kdim = 4096;
constexpr int Ndim = 12288;

constexpr int NKT = Kdim / 64;          // 64 K-tiles of 64 (128 half-steps of 32)
// primary grid: 256x128 tiles
constexpr int GM = Mdim / 256;          // 16
constexpr int GN = Ndim / 128;          // 96
constexpr int NWGP = GM * GN;           // 1536 (divisible by 8)
// fallback grid: 128x128
constexpr int GRID_M = Mdim / 128;      // 32
constexpr int GRID_N = Ndim / 128;      // 96
constexpr int NWG = GRID_M * GRID_N;    // 3072

typedef float  f32x4   __attribute__((ext_vector_type(4)));
typedef __bf16 bf16x4v __attribute__((ext_vector_type(4)));
typedef __bf16 bf16x8v __attribute__((ext_vector_type(8)));
typedef int    i32x4   __attribute__((ext_vector_type(4)));
typedef unsigned short ushort8 __attribute__((ext_vector_type(8)));

// ---------------------------------------------------------------------------
// global_load_lds: per-lane global src, wave-uniform LDS dest (+lane*16).
// NOTE: offset arg kept at 0 ALWAYS — nonzero imm offset was round-6's
// correctness failure suspect; displacement is folded into the global ptr.
// ---------------------------------------------------------------------------
typedef __attribute__((address_space(3))) uint32_t       lds_u32;
typedef __attribute__((address_space(1))) const uint32_t glb_u32;

__device__ __forceinline__ void gload16(const void* g, void* l) {
    __builtin_amdgcn_global_load_lds((glb_u32*)(uintptr_t)g,
                                     (lds_u32*)(uint32_t)(uintptr_t)l, 16, 0, 0);
}

// ===========================================================================
// Swizzle scheme (baked into the prepass global layout):
// within each row, k organized as [kt 0..63][kh 0..1][slot 0..3][elem 0..7];
// logical slot s stored at position s ^ ((row>>1)&3).  One half-step S
// (= 32 k-elems) occupies source bytes [S*64, S*64+64) of each row.
// ===========================================================================

// Pre-pass 1: A fp32 [M][K] -> bf16 [M][K] with baked swizzle
__launch_bounds__(256)
__global__ void cvtA(const float* __restrict__ A, unsigned short* __restrict__ Aw) {
    int t = blockIdx.x * 256 + threadIdx.x;  // one 16B bf16 chunk (8 elems)
    int r = t >> 9;                          // 512 chunks per row
    int c = t & 511;
    const float* src = A + ((long)r << 12) + (c << 3);
    f32x4 v0 = *(const f32x4*)src;
    f32x4 v1 = *(const f32x4*)(src + 4);
    bf16x8v o;
#pragma unroll
    for (int j = 0; j < 4; ++j) { o[j] = (__bf16)v0[j]; o[4 + j] = (__bf16)v1[j]; }
    int ks = c & 3;
    int cp = (c & ~3) | (ks ^ ((r >> 1) & 3));
    *(bf16x8v*)(Aw + ((long)r << 12) + (cp << 3)) = o;
}

// Pre-pass 2: Bq int32 [K][N] + scales -> bf16 B^T [N][K], baked swizzle
__launch_bounds__(256)
__global__ void deqB(const int* __restrict__ Bq, const float* __restrict__ S,
                     unsigned short* __restrict__ Bw) {
    __shared__ unsigned short lt[64][72];    // 144B row pitch -> 16B-aligned chunks
    int kb = blockIdx.x & 63;                // K/64
    int nb = blockIdx.x >> 6;                // N/64
    int k0 = kb << 6, n0 = nb << 6;
    int tid = threadIdx.x;
    int g = k0 >> 7;                         // scale group
    int nq = (tid & 15) << 2;
    f32x4 sc = *(const f32x4*)(S + (long)g * Ndim + n0 + nq);
#pragma unroll
    for (int p = 0; p < 4; ++p) {
        int kk = (p << 4) + (tid >> 4);
        i32x4 q = *(const i32x4*)(Bq + (long)(k0 + kk) * Ndim + n0 + nq);
#pragma unroll
        for (int j = 0; j < 4; ++j) {
            float v = ((float)q[j] - 8.f) * sc[j];
            lt[nq + j][kk] = __builtin_bit_cast(unsigned short, (__bf16)v);
        }
    }
    __syncthreads();
#pragma unroll
    for (int h = 0; h < 2; ++h) {
        int cidx = tid + (h << 8);           // 512 chunks: n 0..63 x (kh,ks)
        int n = cidx >> 3, sidx = cidx & 7;
        int kh = sidx >> 2, ks = sidx & 3;
        int ksp = ks ^ ((n >> 1) & 3);
        ushort8 v = *(const ushort8*)&lt[n][sidx << 3];
        *(ushort8*)(Bw + (long)(n0 + n) * Kdim + k0 + kh * 32 + ksp * 8) = v;
    }
}

// ===========================================================================
// Main GEMM: 256x128 tile, 4 waves (2x2), BK=32 half-steps, 16x16x32 MFMA,
// 3-region LDS rotation (3 x 24 KiB = 72 KiB), stage 2 half-steps ahead,
// counted vmcnt(6); TWO blocks per CU for cross-block MFMA||LDS overlap.
// Region layout: A [256 rows][4 slots x 16B] at +0, B [128][4x16B] at +16384.
// ===========================================================================
__launch_bounds__(256, 2)
__global__ void gemm_p(const unsigned short* __restrict__ Aw,
                       const unsigned short* __restrict__ Bw,
                       float* __restrict__ C) {
    extern __shared__ unsigned char lds[];

    const int tid  = threadIdx.x;
    const int lane = tid & 63;
    const int w    = tid >> 6;               // wave 0..3
    const int wr   = w >> 1, wc = w & 1;     // 2x2 wave grid; wave tile 128x64
    const int fr   = lane & 15;
    const int ks   = lane >> 4;

    // XCD partition: xcd owns 12 tn panels; tm-major within panel
    const int bid = blockIdx.x;
    const int xcd = bid & 7;
    const int loc = bid >> 3;                // 0..191
    const int pn  = loc >> 4;                // 0..11
    const int tm  = loc & 15;                // 0..15
    const int tn  = xcd * 12 + pn;
    const int brow = tm << 8, bcol = tn << 7;

    // staging source pointers: thread -> row = tid>>2 (+64k), pos = tid&3
    const unsigned char* pa0 = (const unsigned char*)Aw
        + (size_t)(brow + (tid >> 2)) * 8192 + (size_t)(tid & 3) * 16;
    const unsigned char* pa1 = pa0 + (size_t)64 * 8192;
    const unsigned char* pa2 = pa0 + (size_t)128 * 8192;
    const unsigned char* pa3 = pa0 + (size_t)192 * 8192;
    const unsigned char* pb0 = (const unsigned char*)Bw
        + (size_t)(bcol + (tid >> 2)) * 8192 + (size_t)(tid & 3) * 16;
    const unsigned char* pb1 = pb0 + (size_t)64 * 8192;
    const int ldw = w << 10;                 // wave's 1KB chunk within a 4KB set

    // fragment read offsets (region-local); conflict-free pattern (r4: PMC=0)
    int offA[8], offB[4];
#pragma unroll
    for (int m = 0; m < 8; ++m) {
        int rA = wr * 128 + m * 16 + fr;
        offA[m] = rA * 64 + ((ks ^ ((rA >> 1) & 3)) << 4);
    }
#pragma unroll
    for (int n = 0; n < 4; ++n) {
        int cB = wc * 64 + n * 16 + fr;
        offB[n] = 16384 + cB * 64 + ((ks ^ ((cB >> 1) & 3)) << 4);
    }

    f32x4 acc[8][4];
#pragma unroll
    for (int m = 0; m < 8; ++m)
#pragma unroll
        for (int n = 0; n < 4; ++n) acc[m][n] = (f32x4){0.f, 0.f, 0.f, 0.f};

// stage A (4 instr) / B (2 instr) of one half-step into region R.
// source displacement OFF is a compile-time constant folded into the pointer;
// builtin offset arg stays 0 (see gload16 note).
#define STAGEA(R, OFF)                                                        \
    gload16(pa0 + (OFF), lds + (R) * 24576 + 0 * 4096 + ldw);                 \
    gload16(pa1 + (OFF), lds + (R) * 24576 + 1 * 4096 + ldw);                 \
    gload16(pa2 + (OFF), lds + (R) * 24576 + 2 * 4096 + ldw);                 \
    gload16(pa3 + (OFF), lds + (R) * 24576 + 3 * 4096 + ldw);
#define STAGEB(R, OFF)                                                        \
    gload16(pb0 + (OFF), lds + (R) * 24576 + 16384 + 0 * 4096 + ldw);         \
    gload16(pb1 + (OFF), lds + (R) * 24576 + 16384 + 1 * 4096 + ldw);

#define RD(R, off) (*(const bf16x8v*)(lds + (R) * 24576 + (off)))

// One half-step: reads region R (data S=3*it+J), stages S+2 into (R+2)%3.
// ph0: A0-3+B0-3 reads, STAGEA, bar, 16 MFMA, bar
// ph1: A4-7 reads,      STAGEB, bar, 16 MFMA, vmcnt, bar
#define HSTEP(R, J, STG, VM)                                                  \
    {                                                                         \
        bf16x8v a[8], b[4];                                                   \
        _Pragma("unroll") for (int m = 0; m < 4; ++m) a[m] = RD(R, offA[m]);  \
        _Pragma("unroll") for (int n = 0; n < 4; ++n) b[n] = RD(R, offB[n]);  \
        if (STG) { STAGEA(((R) + 2) % 3, ((J) + 2) * 64) }                    \
        __builtin_amdgcn_s_barrier();                                         \
        __builtin_amdgcn_s_setprio(1);                                        \
        _Pragma("unroll") for (int m = 0; m < 4; ++m)                         \
            _Pragma("unroll") for (int n = 0; n < 4; ++n)                     \
                acc[m][n] = __builtin_amdgcn_mfma_f32_16x16x32_bf16(          \
                    a[m], b[n], acc[m][n], 0, 0, 0);                          \
        __builtin_amdgcn_s_setprio(0);                                        \
        __builtin_amdgcn_s_barrier();                                         \
        _Pragma("unroll") for (int m = 4; m < 8; ++m) a[m] = RD(R, offA[m]);  \
        if (STG) { STAGEB(((R) + 2) % 3, ((J) + 2) * 64) }                    \
        __builtin_amdgcn_s_barrier();                                         \
        __builtin_amdgcn_s_setprio(1);                                        \
        _Pragma("unroll") for (int m = 4; m < 8; ++m)                         \
            _Pragma("unroll") for (int n = 0; n < 4; ++n)                     \
                acc[m][n] = __builtin_amdgcn_mfma_f32_16x16x32_bf16(          \
                    a[m], b[n], acc[m][n], 0, 0, 0);                          \
        __builtin_amdgcn_s_setprio(0);                                        \
        asm volatile("s_waitcnt vmcnt(" #VM ")" ::: "memory");                \
        __builtin_amdgcn_s_barrier();                                         \
    }

    // prologue: stage S0, S1 (12 instr); vmcnt(6) -> S0 landed
    STAGEA(0, 0) STAGEB(0, 0)
    STAGEA(1, 64) STAGEB(1, 64)
    asm volatile("s_waitcnt vmcnt(6)" ::: "memory");
    __builtin_amdgcn_s_barrier();

    // main: 42 iters x 3 half-steps = steps 0..125 (each stages step S+2)
    for (int it = 0; it < 42; ++it) {
        HSTEP(0, 0, 1, 6)
        HSTEP(1, 1, 1, 6)
        HSTEP(2, 2, 1, 6)
        pa0 += 192; pa1 += 192; pa2 += 192; pa3 += 192;
        pb0 += 192; pb1 += 192;
    }
    // step 126: region 0, no staging, drain all (127 lands)
    HSTEP(0, 0, 0, 0)
    // step 127: region 1, reads + MFMA only
    {
        bf16x8v a[8], b[4];
#pragma unroll
        for (int m = 0; m < 8; ++m) a[m] = RD(1, offA[m]);
#pragma unroll
        for (int n = 0; n < 4; ++n) b[n] = RD(1, offB[n]);
#pragma unroll
        for (int m = 0; m < 8; ++m)
#pragma unroll
            for (int n = 0; n < 4; ++n)
                acc[m][n] = __builtin_amdgcn_mfma_f32_16x16x32_bf16(
                    a[m], b[n], acc[m][n], 0, 0, 0);
    }

    // epilogue: C/D layout col = lane&15, row = (lane>>4)*4 + r
#pragma unroll
    for (int m = 0; m < 8; ++m) {
        int row = brow + wr * 128 + m * 16 + ks * 4;
#pragma unroll
        for (int n = 0; n < 4; ++n) {
            int col = bcol + wc * 64 + n * 16 + fr;
            f32x4 v = acc[m][n];
            float* cp = C + (size_t)row * Ndim + col;
#pragma unroll
            for (int r = 0; r < 4; ++r) cp[(size_t)r * Ndim] = v[r];
        }
    }
#undef HSTEP
#undef RD
#undef STAGEB
#undef STAGEA
}

// ===========================================================================
// Secondary fallback: 128x128 structure (if hipFuncSetAttribute fails)
// ===========================================================================
__launch_bounds__(256, 3)
__global__ void gemm_bf16(const unsigned short* __restrict__ Aw,
                          const unsigned short* __restrict__ Bw,
                          float* __restrict__ C) {
    __shared__ unsigned char sA[128 * 64 * 2];
    __shared__ unsigned char sB[128 * 64 * 2];

    const int tid  = threadIdx.x;
    const int lane = tid & 63;
    const int w    = tid >> 6;

    const int bid   = blockIdx.x;
    const int x     = bid & 7;
    const int local = bid >> 3;
    const int pn    = local >> 5;
    const int tm    = local & 31;
    const int tn    = x * 12 + pn;
    const int brow  = tm << 7;
    const int bcol  = tn << 7;

    const unsigned char* ga[4];
    const unsigned char* gb[4];
#pragma unroll
    for (int i = 0; i < 4; ++i) {
        int c = (w << 8) + (i << 6) + lane;
        int r = c >> 3, s = c & 7;
        ga[i] = (const unsigned char*)Aw + (long)(brow + r) * 8192 + (s << 4);
        gb[i] = (const unsigned char*)Bw + (long)(bcol + r) * 8192 + (s << 4);
    }

    const int fr = lane & 15;
    const int ks = lane >> 4;
    const int wr = w >> 1, wc = w & 1;
    int ra[4][2], rb[4][2];
#pragma unroll
    for (int m = 0; m < 4; ++m)
#pragma unroll
        for (int kk = 0; kk < 2; ++kk) {
            int r_a = wr * 64 + m * 16 + fr;
            int r_b = wc * 64 + m * 16 + fr;
            ra[m][kk] = (r_a << 7) + (kk << 6) + ((ks ^ ((r_a >> 1) & 3)) << 4);
            rb[m][kk] = (r_b << 7) + (kk << 6) + ((ks ^ ((r_b >> 1) & 3)) << 4);
        }

    f32x4 acc[4][4];
#pragma unroll
    for (int m = 0; m < 4; ++m)
#pragma unroll
        for (int n = 0; n < 4; ++n) acc[m][n] = (f32x4){0.f, 0.f, 0.f, 0.f};

    for (int kt = 0; kt < NKT; ++kt) {
#pragma unroll
        for (int i = 0; i < 4; ++i) {
            gload16(ga[i], sA + (((w << 2) + i) << 10));
            gload16(gb[i], sB + (((w << 2) + i) << 10));
            ga[i] += 128;
            gb[i] += 128;
        }
        __syncthreads();

#pragma unroll
        for (int kk = 0; kk < 2; ++kk) {
            bf16x8v af[4], bf[4];
#pragma unroll
            for (int m = 0; m < 4; ++m) af[m] = *(const bf16x8v*)(sA + ra[m][kk]);
#pragma unroll
            for (int n = 0; n < 4; ++n) bf[n] = *(const bf16x8v*)(sB + rb[n][kk]);
#pragma unroll
            for (int m = 0; m < 4; ++m)
#pragma unroll
                for (int n = 0; n < 4; ++n)
                    acc[m][n] = __builtin_amdgcn_mfma_f32_16x16x32_bf16(af[m], bf[n], acc[m][n], 0, 0, 0);
        }
        __syncthreads();
    }

#pragma unroll
    for (int m = 0; m < 4; ++m) {
        int row = brow + wr * 64 + m * 16 + ks * 4;
#pragma unroll
        for (int n = 0; n < 4; ++n) {
            int col = bcol + wc * 64 + n * 16 + fr;
            f32x4 v = acc[m][n];
            float* cp = C + (long)row * Ndim + col;
#pragma unroll
            for (int r = 0; r < 4; ++r) cp[(long)r * Ndim] = v[r];
        }
    }
}

// ===========================================================================
// Last-resort fallback: fused single-pass (no workspace needed)
// ===========================================================================
__device__ __forceinline__ int swz_f(int row, int kbyte) {
    int s = kbyte >> 4;
    int f = s ^ ((row ^ (row >> 2)) & 7);
    return (row << 7) + (f << 4) + (kbyte & 15);
}

__launch_bounds__(256, 2)
__global__ void machete_fused(const float* __restrict__ A,
                              const int* __restrict__ Bq,
                              const float* __restrict__ S,
                              float* __restrict__ C) {
    __shared__ unsigned char sA[128 * 64 * 2];
    __shared__ unsigned char sB[128 * 64 * 2];

    const int tid = threadIdx.x;
    const int bid = blockIdx.x;
    const int sid = (bid & 7) * (NWG / 8) + (bid >> 3);
    const int tm = sid / GRID_N;
    const int tn = sid % GRID_N;
    const int brow = tm * 128;
    const int bcol = tn * 128;

    const int a_row0 = tid >> 4;
    const int a_kb   = tid & 15;
    const int b_kb = tid >> 4;
    const int b_nb = tid & 15;

    int aw[8];
#pragma unroll
    for (int i = 0; i < 8; ++i) aw[i] = swz_f(a_row0 + 16 * i, a_kb * 8);
    int bw[2][4];
#pragma unroll
    for (int i = 0; i < 2; ++i)
#pragma unroll
        for (int j = 0; j < 4; ++j) bw[i][j] = swz_f(4 * b_nb + 64 * i + j, b_kb * 8);

    const int lane = tid & 63;
    const int w  = tid >> 6;
    const int wr = w >> 1, wc = w & 1;
    const int fr = lane & 15;
    const int ks = lane >> 4;
    int ar[4][2], br[4][2];
#pragma unroll
    for (int m = 0; m < 4; ++m)
#pragma unroll
        for (int kk = 0; kk < 2; ++kk) {
            ar[m][kk] = swz_f(wr * 64 + m * 16 + fr, kk * 64 + ks * 16);
            br[m][kk] = swz_f(wc * 64 + m * 16 + fr, kk * 64 + ks * 16);
        }

    const float* Ap = A + (long)brow * Kdim;
    const int*   Bp = Bq + bcol;

    f32x4 aregs[8];
    i32x4 bregs[2][4];
    f32x4 sregs[2];

#pragma unroll
    for (int i = 0; i < 8; ++i)
        aregs[i] = *(const f32x4*)(Ap + (long)(a_row0 + 16 * i) * Kdim + a_kb * 4);
#pragma unroll
    for (int i = 0; i < 2; ++i) {
#pragma unroll
        for (int r = 0; r < 4; ++r)
            bregs[i][r] = *(const i32x4*)(Bp + (long)(b_kb * 4 + r) * Ndim + 4 * b_nb + 64 * i);
        sregs[i] = *(const f32x4*)(S + bcol + 4 * b_nb + 64 * i);
    }

    f32x4 acc[4][4];
#pragma unroll
    for (int m = 0; m < 4; ++m)
#pragma unroll
        for (int n = 0; n < 4; ++n) acc[m][n] = (f32x4){0.f, 0.f, 0.f, 0.f};

    for (int kt = 0; kt < NKT; ++kt) {
#pragma unroll
        for (int i = 0; i < 8; ++i) {
            f32x4 v = aregs[i];
            bf16x4v p;
            p[0] = (__bf16)v[0]; p[1] = (__bf16)v[1];
            p[2] = (__bf16)v[2]; p[3] = (__bf16)v[3];
            *(bf16x4v*)(sA + aw[i]) = p;
        }
#pragma unroll
        for (int i = 0; i < 2; ++i) {
            f32x4 sc = sregs[i];
#pragma unroll
            for (int j = 0; j < 4; ++j) {
                float scj = sc[j];
                float nm8 = -8.f * scj;
                bf16x4v p;
#pragma unroll
                for (int r = 0; r < 4; ++r) {
                    float v = (float)bregs[i][r][j] * scj + nm8;
                    p[r] = (__bf16)v;
                }
                *(bf16x4v*)(sB + bw[i][j]) = p;
            }
        }
        __syncthreads();

        if (kt + 1 < NKT) {
            const float* Ap2 = Ap + (kt + 1) * 64;
            const int*   Bp2 = Bq + bcol + (long)((kt + 1) * 64) * Ndim;
            const float* Sp2 = S + (long)((kt + 1) >> 1) * Ndim + bcol;
#pragma unroll
            for (int i = 0; i < 8; ++i)
                aregs[i] = *(const f32x4*)(Ap2 + (long)(a_row0 + 16 * i) * Kdim + a_kb * 4);
#pragma unroll
            for (int i = 0; i < 2; ++i) {
#pragma unroll
                for (int r = 0; r < 4; ++r)
                    bregs[i][r] = *(const i32x4*)(Bp2 + (long)(b_kb * 4 + r) * Ndim + 4 * b_nb + 64 * i);
                sregs[i] = *(const f32x4*)(Sp2 + 4 * b_nb + 64 * i);
            }
        }

#pragma unroll
        for (int kk = 0; kk < 2; ++kk) {
            bf16x8v af[4], bfv[4];
#pragma unroll
            for (int m = 0; m < 4; ++m) af[m] = *(const bf16x8v*)(sA + ar[m][kk]);
#pragma unroll
            for (int n = 0; n < 4; ++n) bfv[n] = *(const bf16x8v*)(sB + br[n][kk]);
#pragma unroll
            for (int m = 0; m < 4; ++m)
#pragma unroll
                for (int n = 0; n < 4; ++n)
                    acc[m][n] = __builtin_amdgcn_mfma_f32_16x16x32_bf16(af[m], bfv[n], acc[m][n], 0, 0, 0);
        }
        __syncthreads();
    }

#pragma unroll
    for (int m = 0; m < 4; ++m) {
        int row = brow + wr * 64 + m * 16 + ks * 4;
#pragma unroll
        for (int n = 0; n < 4; ++n) {
            int col = bcol + wc * 64 + n * 16 + fr;
            f32x4 v = acc[m][n];
            float* cp = C + (long)row * Ndim + col;
#pragma unroll
            for (int r = 0; r < 4; ++r) cp[(long)r * Ndim] = v[r];
        }
    }
}

extern "C" void kernel_launch(void* const* d_in, const int* in_sizes, int n_in,
                              void* d_out, int out_size, void* d_ws, size_t ws_size,
                              hipStream_t stream) {
    const float* A  = (const float*)d_in[0];
    const int*   Bq = (const int*)d_in[1];
    const float* S  = (const float*)d_in[2];
    float* C = (float*)d_out;

    const size_t a_elems = (size_t)Mdim * Kdim;
    const size_t b_elems = (size_t)Ndim * Kdim;
    const size_t need = (a_elems + b_elems) * sizeof(unsigned short);

    if (ws_size >= need) {
        unsigned short* Aw = (unsigned short*)d_ws;
        unsigned short* Bw = Aw + a_elems;
        hipLaunchKernelGGL(cvtA, dim3((Mdim * Kdim / 8) / 256), dim3(256), 0, stream, A, Aw);
        hipLaunchKernelGGL(deqB, dim3((Kdim / 64) * (Ndim / 64)), dim3(256), 0, stream, Bq, S, Bw);
        hipError_t e = hipFuncSetAttribute(
            reinterpret_cast<const void*>(gemm_p),
            hipFuncAttributeMaxDynamicSharedMemorySize, 73728);
        if (e == hipSuccess) {
            hipLaunchKernelGGL(gemm_p, dim3(NWGP), dim3(256), 73728, stream, Aw, Bw, C);
        } else {
            hipLaunchKernelGGL(gemm_bf16, dim3(NWG), dim3(256), 0, stream, Aw, Bw, C);
        }
    } else {
        hipLaunchKernelGGL(machete_fused, dim3(NWG), dim3(256), 0, stream, A, Bq, S, C);
    }
}

// Round 8
// 468.299 us; speedup vs baseline: 1.1050x; 1.1050x over previous
//
#include <hip/hip_runtime.h>
#include <hip/hip_bf16.h>
#include <stdint.h>

// Problem constants (fixed by reference: M=4096, K=4096, N=12288, group=128)
constexpr int Mdim = 4096;
constexpr int Kdim = 4096;
constexpr int Ndim = 12288;

constexpr int NKT = Kdim / 64;          // 64 K-tiles of BK=64
constexpr int GM256 = Mdim / 256;       // 16
constexpr int GN256 = Ndim / 256;       // 48
constexpr int NWG256 = GM256 * GN256;   // 768 (divisible by 8)
constexpr int GRID_M = Mdim / 128;      // 32
constexpr int GRID_N = Ndim / 128;      // 96
constexpr int NWG = GRID_M * GRID_N;    // 3072

typedef float  f32x4   __attribute__((ext_vector_type(4)));
typedef __bf16 bf16x4v __attribute__((ext_vector_type(4)));
typedef __bf16 bf16x8v __attribute__((ext_vector_type(8)));
typedef int    i32x4   __attribute__((ext_vector_type(4)));
typedef unsigned short ushort8 __attribute__((ext_vector_type(8)));

// ---------------------------------------------------------------------------
// global_load_lds: per-lane global src, wave-uniform LDS dest (+lane*16).
// PLATFORM NOTE (round 6/7 A/B): the builtin's `offset` arg corrupts the
// transfer — ALWAYS pass 0 and fold displacement into the global pointer.
// ---------------------------------------------------------------------------
typedef __attribute__((address_space(3))) uint32_t       lds_u32;
typedef __attribute__((address_space(1))) const uint32_t glb_u32;

__device__ __forceinline__ void gload16(const void* g, void* l) {
    __builtin_amdgcn_global_load_lds((glb_u32*)(uintptr_t)g,
                                     (lds_u32*)(uint32_t)(uintptr_t)l, 16, 0, 0);
}

// ===========================================================================
// Swizzle scheme (baked into the prepass global layout):
// within each row, k organized as [kt 0..63][kh 0..1][slot 0..3][elem 0..7];
// logical slot s stored at position s ^ ((row>>1)&3).
// 16-row x 4-slot fragment read pattern is PMC-verified conflict-free.
// ===========================================================================

// Pre-pass 1: A fp32 [M][K] -> bf16 [M][K] with baked swizzle
__launch_bounds__(256)
__global__ void cvtA(const float* __restrict__ A, unsigned short* __restrict__ Aw) {
    int t = blockIdx.x * 256 + threadIdx.x;  // one 16B bf16 chunk (8 elems)
    int r = t >> 9;                          // 512 chunks per row
    int c = t & 511;
    const float* src = A + ((long)r << 12) + (c << 3);
    f32x4 v0 = *(const f32x4*)src;
    f32x4 v1 = *(const f32x4*)(src + 4);
    bf16x8v o;
#pragma unroll
    for (int j = 0; j < 4; ++j) { o[j] = (__bf16)v0[j]; o[4 + j] = (__bf16)v1[j]; }
    int ks = c & 3;
    int cp = (c & ~3) | (ks ^ ((r >> 1) & 3));
    *(bf16x8v*)(Aw + ((long)r << 12) + (cp << 3)) = o;
}

// Pre-pass 2: Bq int32 [K][N] + scales -> bf16 B^T [N][K], baked swizzle
__launch_bounds__(256)
__global__ void deqB(const int* __restrict__ Bq, const float* __restrict__ S,
                     unsigned short* __restrict__ Bw) {
    __shared__ unsigned short lt[64][72];    // 144B row pitch -> 16B-aligned chunks
    int kb = blockIdx.x & 63;                // K/64
    int nb = blockIdx.x >> 6;                // N/64
    int k0 = kb << 6, n0 = nb << 6;
    int tid = threadIdx.x;
    int g = k0 >> 7;                         // scale group
    int nq = (tid & 15) << 2;
    f32x4 sc = *(const f32x4*)(S + (long)g * Ndim + n0 + nq);
#pragma unroll
    for (int p = 0; p < 4; ++p) {
        int kk = (p << 4) + (tid >> 4);
        i32x4 q = *(const i32x4*)(Bq + (long)(k0 + kk) * Ndim + n0 + nq);
#pragma unroll
        for (int j = 0; j < 4; ++j) {
            float v = ((float)q[j] - 8.f) * sc[j];
            lt[nq + j][kk] = __builtin_bit_cast(unsigned short, (__bf16)v);
        }
    }
    __syncthreads();
#pragma unroll
    for (int h = 0; h < 2; ++h) {
        int cidx = tid + (h << 8);           // 512 chunks: n 0..63 x (kh,ks)
        int n = cidx >> 3, sidx = cidx & 7;
        int kh = sidx >> 2, ks = sidx & 3;
        int ksp = ks ^ ((n >> 1) & 3);
        ushort8 v = *(const ushort8*)&lt[n][sidx << 3];
        *(ushort8*)(Bw + (long)(n0 + n) * Kdim + k0 + kh * 32 + ksp * 8) = v;
    }
}

// ===========================================================================
// Main GEMM: 256x256 tile, BK=64, 8 waves (2Mx4N), 16x16x32 MFMA,
// TWO fat halves per K-tile (32-MFMA clusters), MINIMAL SYNC:
// 2 barriers + 1 counted vmcnt(4) per K-tile (hazard-derived; see notes).
// 128 KiB double-buffered LDS: buf b at b<<16; A [kh<<14][256r][4x16B],
// B at +32768 same shape.
// ===========================================================================
__launch_bounds__(512, 2)
__global__ void gemm256(const unsigned short* __restrict__ Aw,
                        const unsigned short* __restrict__ Bw,
                        float* __restrict__ C) {
    extern __shared__ unsigned char ldsbuf[];

    const int tid  = threadIdx.x;
    const int lane = tid & 63;
    const int w    = tid >> 6;               // wave 0..7
    const int wr   = w >> 2, wc = w & 3;     // 2x4 wave grid; wave tile 128x64
    const int fr   = lane & 15;
    const int ks   = lane >> 4;

    // XCD partition: xcd owns 6 tn panels; tm-major within panel
    const int bid = blockIdx.x;
    const int xcd = bid & 7;
    const int loc = bid >> 3;                // 0..95
    const int pn  = loc >> 4;                // 0..5
    const int tm  = loc & 15;                // 0..15
    const int tn  = xcd * 6 + pn;
    const int brow = tm << 8, bcol = tn << 8;

    // staging source pointers: thread covers chunk tid (rows 0-127) and
    // chunk tid+512 (rows 128-255) of each (tile,kh) half.
    const unsigned char* pA = (const unsigned char*)Aw
        + (size_t)(brow + (tid >> 2)) * 8192 + (size_t)(tid & 3) * 16;
    const unsigned char* pA2 = pA + (size_t)128 * 8192;
    const unsigned char* pB = (const unsigned char*)Bw
        + (size_t)(bcol + (tid >> 2)) * 8192 + (size_t)(tid & 3) * 16;
    const unsigned char* pB2 = pB + (size_t)128 * 8192;
    const int ldw = w << 10;                 // wave's 1KB chunk within a region

    // fragment read offsets (region-local); PMC-verified conflict-free
    int offA[8][2], offB[4][2];
#pragma unroll
    for (int am = 0; am < 8; ++am)
#pragma unroll
        for (int kh = 0; kh < 2; ++kh) {
            int rowL = wr * 128 + am * 16 + fr;
            offA[am][kh] = (kh << 14) + rowL * 64 + ((ks ^ ((rowL >> 1) & 3)) << 4);
        }
#pragma unroll
    for (int n = 0; n < 4; ++n)
#pragma unroll
        for (int kh = 0; kh < 2; ++kh) {
            int colL = wc * 64 + n * 16 + fr;
            offB[n][kh] = (kh << 14) + colL * 64 + ((ks ^ ((colL >> 1) & 3)) << 4);
        }

    f32x4 acc[8][4];
#pragma unroll
    for (int m = 0; m < 8; ++m)
#pragma unroll
        for (int n = 0; n < 4; ++n) acc[m][n] = (f32x4){0.f, 0.f, 0.f, 0.f};

// stage one (tile,kh) half of A / B into region DSTB (= buf<<16 | kh<<14).
#define STG_A(DSTB, OFF)                                                      \
    gload16(pA  + (OFF), ldsbuf + (DSTB) + ldw);                              \
    gload16(pA2 + (OFF), ldsbuf + (DSTB) + ldw + 8192);
#define STG_B(DSTB, OFF)                                                      \
    gload16(pB  + (OFF), ldsbuf + (DSTB) + 32768 + ldw);                      \
    gload16(pB2 + (OFF), ldsbuf + (DSTB) + 32768 + ldw + 8192);

// One K-tile, minimal-sync:
//  half0: 12 ds_reads (kh0) | stage {A,B}(T+1,kh1) | 32 MFMA
//  BARRIER + sched pin   (all kh0 reads done -> safe to overwrite kh0)
//  half1: 12 ds_reads (kh1) | stage {A,B}(T+2,kh0) | 32 MFMA
//  vmcnt(VM) + BARRIER   (T+1 data fully landed; swap buffers)
#define TILE(BUF, O1, O2, STG1, STG2, VM)                                     \
    {                                                                         \
        unsigned char* sAc = ldsbuf + ((BUF) << 16);                          \
        unsigned char* sBc = sAc + 32768;                                     \
        bf16x8v aF[8], bF[4];                                                 \
        _Pragma("unroll") for (int m = 0; m < 8; ++m)                         \
            aF[m] = *(const bf16x8v*)(sAc + offA[m][0]);                      \
        _Pragma("unroll") for (int n = 0; n < 4; ++n)                         \
            bF[n] = *(const bf16x8v*)(sBc + offB[n][0]);                      \
        if (STG1) { STG_A(((1 - (BUF)) << 16) + (1 << 14), O1)                \
                    STG_B(((1 - (BUF)) << 16) + (1 << 14), O1) }              \
        __builtin_amdgcn_s_setprio(1);                                        \
        _Pragma("unroll") for (int m = 0; m < 8; ++m)                         \
            _Pragma("unroll") for (int n = 0; n < 4; ++n)                     \
                acc[m][n] = __builtin_amdgcn_mfma_f32_16x16x32_bf16(          \
                    aF[m], bF[n], acc[m][n], 0, 0, 0);                        \
        __builtin_amdgcn_s_setprio(0);                                        \
        __builtin_amdgcn_s_barrier();                                         \
        __builtin_amdgcn_sched_barrier(0);  /* pin: no hoist above WAR bar */ \
        _Pragma("unroll") for (int m = 0; m < 8; ++m)                         \
            aF[m] = *(const bf16x8v*)(sAc + offA[m][1]);                      \
        _Pragma("unroll") for (int n = 0; n < 4; ++n)                         \
            bF[n] = *(const bf16x8v*)(sBc + offB[n][1]);                      \
        if (STG2) { STG_A(((BUF) << 16), O2)                                  \
                    STG_B(((BUF) << 16), O2) }                                \
        __builtin_amdgcn_s_setprio(1);                                        \
        _Pragma("unroll") for (int m = 0; m < 8; ++m)                         \
            _Pragma("unroll") for (int n = 0; n < 4; ++n)                     \
                acc[m][n] = __builtin_amdgcn_mfma_f32_16x16x32_bf16(          \
                    aF[m], bF[n], acc[m][n], 0, 0, 0);                        \
        __builtin_amdgcn_s_setprio(0);                                        \
        asm volatile("s_waitcnt vmcnt(" #VM ")" ::: "memory");                \
        __builtin_amdgcn_s_barrier();                                         \
    }

    // prologue: {A,B}(0,kh0), {A,B}(0,kh1), {A,B}(1,kh0); vmcnt(4) -> T0 landed
    STG_A(0, 0)                 STG_B(0, 0)
    STG_A((1 << 14), 64)        STG_B((1 << 14), 64)
    STG_A((1 << 16), 128)       STG_B((1 << 16), 128)
    asm volatile("s_waitcnt vmcnt(4)" ::: "memory");
    __builtin_amdgcn_s_barrier();

    // main loop: tiles 0..61 as unrolled pairs (31 iters)
    for (int it = 0; it < 31; ++it) {
        TILE(0, 192, 256, 1, 1, 4)
        TILE(1, 320, 384, 1, 1, 4)
        pA += 256; pA2 += 256; pB += 256; pB2 += 256;
    }
    // tile 62 (buf0): stage only (63,kh1); drain everything
    TILE(0, 192, 0, 1, 0, 0)
    // tile 63 (buf1): reads + MFMA only
    {
        unsigned char* sAc = ldsbuf + (1 << 16);
        unsigned char* sBc = sAc + 32768;
#pragma unroll
        for (int kh = 0; kh < 2; ++kh) {
            bf16x8v aF[8], bF[4];
#pragma unroll
            for (int m = 0; m < 8; ++m) aF[m] = *(const bf16x8v*)(sAc + offA[m][kh]);
#pragma unroll
            for (int n = 0; n < 4; ++n) bF[n] = *(const bf16x8v*)(sBc + offB[n][kh]);
#pragma unroll
            for (int m = 0; m < 8; ++m)
#pragma unroll
                for (int n = 0; n < 4; ++n)
                    acc[m][n] = __builtin_amdgcn_mfma_f32_16x16x32_bf16(
                        aF[m], bF[n], acc[m][n], 0, 0, 0);
        }
    }

    // epilogue: C/D layout col = lane&15, row = (lane>>4)*4 + r
#pragma unroll
    for (int m = 0; m < 8; ++m) {
        int row = brow + wr * 128 + m * 16 + ks * 4;
#pragma unroll
        for (int n = 0; n < 4; ++n) {
            int col = bcol + wc * 64 + n * 16 + fr;
            f32x4 v = acc[m][n];
            float* cp = C + (size_t)row * Ndim + col;
#pragma unroll
            for (int r = 0; r < 4; ++r) cp[(size_t)r * Ndim] = v[r];
        }
    }
#undef TILE
#undef STG_B
#undef STG_A
}

// ===========================================================================
// Secondary fallback: 128x128 structure (if hipFuncSetAttribute fails)
// ===========================================================================
__launch_bounds__(256, 3)
__global__ void gemm_bf16(const unsigned short* __restrict__ Aw,
                          const unsigned short* __restrict__ Bw,
                          float* __restrict__ C) {
    __shared__ unsigned char sA[128 * 64 * 2];
    __shared__ unsigned char sB[128 * 64 * 2];

    const int tid  = threadIdx.x;
    const int lane = tid & 63;
    const int w    = tid >> 6;

    const int bid   = blockIdx.x;
    const int x     = bid & 7;
    const int local = bid >> 3;
    const int pn    = local >> 5;
    const int tm    = local & 31;
    const int tn    = x * 12 + pn;
    const int brow  = tm << 7;
    const int bcol  = tn << 7;

    const unsigned char* ga[4];
    const unsigned char* gb[4];
#pragma unroll
    for (int i = 0; i < 4; ++i) {
        int c = (w << 8) + (i << 6) + lane;
        int r = c >> 3, s = c & 7;
        ga[i] = (const unsigned char*)Aw + (long)(brow + r) * 8192 + (s << 4);
        gb[i] = (const unsigned char*)Bw + (long)(bcol + r) * 8192 + (s << 4);
    }

    const int fr = lane & 15;
    const int ks = lane >> 4;
    const int wr = w >> 1, wc = w & 1;
    int ra[4][2], rb[4][2];
#pragma unroll
    for (int m = 0; m < 4; ++m)
#pragma unroll
        for (int kk = 0; kk < 2; ++kk) {
            int r_a = wr * 64 + m * 16 + fr;
            int r_b = wc * 64 + m * 16 + fr;
            ra[m][kk] = (r_a << 7) + (kk << 6) + ((ks ^ ((r_a >> 1) & 3)) << 4);
            rb[m][kk] = (r_b << 7) + (kk << 6) + ((ks ^ ((r_b >> 1) & 3)) << 4);
        }

    f32x4 acc[4][4];
#pragma unroll
    for (int m = 0; m < 4; ++m)
#pragma unroll
        for (int n = 0; n < 4; ++n) acc[m][n] = (f32x4){0.f, 0.f, 0.f, 0.f};

    for (int kt = 0; kt < NKT; ++kt) {
#pragma unroll
        for (int i = 0; i < 4; ++i) {
            gload16(ga[i], sA + (((w << 2) + i) << 10));
            gload16(gb[i], sB + (((w << 2) + i) << 10));
            ga[i] += 128;
            gb[i] += 128;
        }
        __syncthreads();

#pragma unroll
        for (int kk = 0; kk < 2; ++kk) {
            bf16x8v af[4], bf[4];
#pragma unroll
            for (int m = 0; m < 4; ++m) af[m] = *(const bf16x8v*)(sA + ra[m][kk]);
#pragma unroll
            for (int n = 0; n < 4; ++n) bf[n] = *(const bf16x8v*)(sB + rb[n][kk]);
#pragma unroll
            for (int m = 0; m < 4; ++m)
#pragma unroll
                for (int n = 0; n < 4; ++n)
                    acc[m][n] = __builtin_amdgcn_mfma_f32_16x16x32_bf16(af[m], bf[n], acc[m][n], 0, 0, 0);
        }
        __syncthreads();
    }

#pragma unroll
    for (int m = 0; m < 4; ++m) {
        int row = brow + wr * 64 + m * 16 + ks * 4;
#pragma unroll
        for (int n = 0; n < 4; ++n) {
            int col = bcol + wc * 64 + n * 16 + fr;
            f32x4 v = acc[m][n];
            float* cp = C + (long)row * Ndim + col;
#pragma unroll
            for (int r = 0; r < 4; ++r) cp[(long)r * Ndim] = v[r];
        }
    }
}

// ===========================================================================
// Last-resort fallback: fused single-pass (no workspace needed)
// ===========================================================================
__device__ __forceinline__ int swz_f(int row, int kbyte) {
    int s = kbyte >> 4;
    int f = s ^ ((row ^ (row >> 2)) & 7);
    return (row << 7) + (f << 4) + (kbyte & 15);
}

__launch_bounds__(256, 2)
__global__ void machete_fused(const float* __restrict__ A,
                              const int* __restrict__ Bq,
                              const float* __restrict__ S,
                              float* __restrict__ C) {
    __shared__ unsigned char sA[128 * 64 * 2];
    __shared__ unsigned char sB[128 * 64 * 2];

    const int tid = threadIdx.x;
    const int bid = blockIdx.x;
    const int sid = (bid & 7) * (NWG / 8) + (bid >> 3);
    const int tm = sid / GRID_N;
    const int tn = sid % GRID_N;
    const int brow = tm * 128;
    const int bcol = tn * 128;

    const int a_row0 = tid >> 4;
    const int a_kb   = tid & 15;
    const int b_kb = tid >> 4;
    const int b_nb = tid & 15;

    int aw[8];
#pragma unroll
    for (int i = 0; i < 8; ++i) aw[i] = swz_f(a_row0 + 16 * i, a_kb * 8);
    int bw[2][4];
#pragma unroll
    for (int i = 0; i < 2; ++i)
#pragma unroll
        for (int j = 0; j < 4; ++j) bw[i][j] = swz_f(4 * b_nb + 64 * i + j, b_kb * 8);

    const int lane = tid & 63;
    const int w  = tid >> 6;
    const int wr = w >> 1, wc = w & 1;
    const int fr = lane & 15;
    const int ks = lane >> 4;
    int ar[4][2], br[4][2];
#pragma unroll
    for (int m = 0; m < 4; ++m)
#pragma unroll
        for (int kk = 0; kk < 2; ++kk) {
            ar[m][kk] = swz_f(wr * 64 + m * 16 + fr, kk * 64 + ks * 16);
            br[m][kk] = swz_f(wc * 64 + m * 16 + fr, kk * 64 + ks * 16);
        }

    const float* Ap = A + (long)brow * Kdim;
    const int*   Bp = Bq + bcol;

    f32x4 aregs[8];
    i32x4 bregs[2][4];
    f32x4 sregs[2];

#pragma unroll
    for (int i = 0; i < 8; ++i)
        aregs[i] = *(const f32x4*)(Ap + (long)(a_row0 + 16 * i) * Kdim + a_kb * 4);
#pragma unroll
    for (int i = 0; i < 2; ++i) {
#pragma unroll
        for (int r = 0; r < 4; ++r)
            bregs[i][r] = *(const i32x4*)(Bp + (long)(b_kb * 4 + r) * Ndim + 4 * b_nb + 64 * i);
        sregs[i] = *(const f32x4*)(S + bcol + 4 * b_nb + 64 * i);
    }

    f32x4 acc[4][4];
#pragma unroll
    for (int m = 0; m < 4; ++m)
#pragma unroll
        for (int n = 0; n < 4; ++n) acc[m][n] = (f32x4){0.f, 0.f, 0.f, 0.f};

    for (int kt = 0; kt < NKT; ++kt) {
#pragma unroll
        for (int i = 0; i < 8; ++i) {
            f32x4 v = aregs[i];
            bf16x4v p;
            p[0] = (__bf16)v[0]; p[1] = (__bf16)v[1];
            p[2] = (__bf16)v[2]; p[3] = (__bf16)v[3];
            *(bf16x4v*)(sA + aw[i]) = p;
        }
#pragma unroll
        for (int i = 0; i < 2; ++i) {
            f32x4 sc = sregs[i];
#pragma unroll
            for (int j = 0; j < 4; ++j) {
                float scj = sc[j];
                float nm8 = -8.f * scj;
                bf16x4v p;
#pragma unroll
                for (int r = 0; r < 4; ++r) {
                    float v = (float)bregs[i][r][j] * scj + nm8;
                    p[r] = (__bf16)v;
                }
                *(bf16x4v*)(sB + bw[i][j]) = p;
            }
        }
        __syncthreads();

        if (kt + 1 < NKT) {
            const float* Ap2 = Ap + (kt + 1) * 64;
            const int*   Bp2 = Bq + bcol + (long)((kt + 1) * 64) * Ndim;
            const float* Sp2 = S + (long)((kt + 1) >> 1) * Ndim + bcol;
#pragma unroll
            for (int i = 0; i < 8; ++i)
                aregs[i] = *(const f32x4*)(Ap2 + (long)(a_row0 + 16 * i) * Kdim + a_kb * 4);
#pragma unroll
            for (int i = 0; i < 2; ++i) {
#pragma unroll
                for (int r = 0; r < 4; ++r)
                    bregs[i][r] = *(const i32x4*)(Bp2 + (long)(b_kb * 4 + r) * Ndim + 4 * b_nb + 64 * i);
                sregs[i] = *(const f32x4*)(Sp2 + 4 * b_nb + 64 * i);
            }
        }

#pragma unroll
        for (int kk = 0; kk < 2; ++kk) {
            bf16x8v af[4], bfv[4];
#pragma unroll
            for (int m = 0; m < 4; ++m) af[m] = *(const bf16x8v*)(sA + ar[m][kk]);
#pragma unroll
            for (int n = 0; n < 4; ++n) bfv[n] = *(const bf16x8v*)(sB + br[n][kk]);
#pragma unroll
            for (int m = 0; m < 4; ++m)
#pragma unroll
                for (int n = 0; n < 4; ++n)
                    acc[m][n] = __builtin_amdgcn_mfma_f32_16x16x32_bf16(af[m], bfv[n], acc[m][n], 0, 0, 0);
        }
        __syncthreads();
    }

#pragma unroll
    for (int m = 0; m < 4; ++m) {
        int row = brow + wr * 64 + m * 16 + ks * 4;
#pragma unroll
        for (int n = 0; n < 4; ++n) {
            int col = bcol + wc * 64 + n * 16 + fr;
            f32x4 v = acc[m][n];
            float* cp = C + (long)row * Ndim + col;
#pragma unroll
            for (int r = 0; r < 4; ++r) cp[(long)r * Ndim] = v[r];
        }
    }
}

extern "C" void kernel_launch(void* const* d_in, const int* in_sizes, int n_in,
                              void* d_out, int out_size, void* d_ws, size_t ws_size,
                              hipStream_t stream) {
    const float* A  = (const float*)d_in[0];
    const int*   Bq = (const int*)d_in[1];
    const float* S  = (const float*)d_in[2];
    float* C = (float*)d_out;

    const size_t a_elems = (size_t)Mdim * Kdim;
    const size_t b_elems = (size_t)Ndim * Kdim;
    const size_t need = (a_elems + b_elems) * sizeof(unsigned short);

    if (ws_size >= need) {
        unsigned short* Aw = (unsigned short*)d_ws;
        unsigned short* Bw = Aw + a_elems;
        hipLaunchKernelGGL(cvtA, dim3((Mdim * Kdim / 8) / 256), dim3(256), 0, stream, A, Aw);
        hipLaunchKernelGGL(deqB, dim3((Kdim / 64) * (Ndim / 64)), dim3(256), 0, stream, Bq, S, Bw);
        hipError_t e = hipFuncSetAttribute(
            reinterpret_cast<const void*>(gemm256),
            hipFuncAttributeMaxDynamicSharedMemorySize, 131072);
        if (e == hipSuccess) {
            hipLaunchKernelGGL(gemm256, dim3(NWG256), dim3(512), 131072, stream, Aw, Bw, C);
        } else {
            hipLaunchKernelGGL(gemm_bf16, dim3(NWG), dim3(256), 0, stream, Aw, Bw, C);
        }
    } else {
        hipLaunchKernelGGL(machete_fused, dim3(NWG), dim3(256), 0, stream, A, Bq, S, C);
    }
}